// Round 1
// baseline (140.837 us; speedup 1.0000x reference)
//
#include <hip/hip_runtime.h>

#define Bn 32
#define Cn 64
#define Hn 56
#define Wn 56
#define REPN 50
#define NKn 17
#define HWn (Hn*Wn)           // 3136
#define NSTATf 100352.0f      // B*H*W
#define EPSf 1e-5f

// LDS tile: rows cover padded-input rows -2..57 (60 rows), cols -2..57 at
// col offset 4 (data at col 4+ix) so float4 stores are 16B aligned; stride 64.
#define TSTR 64
#define TROWS 60
#define TSZ (TROWS*TSTR)

#define WEFF_OFF 0        // REPN*63 = 3150 floats: [r][t(7)][9]
#define STATS_OFF 3200    // 6*REPN = 300 floats: [q(6)][r]

// ---------------------------------------------------------------- K0: weights
// Weff[r][t][ij] = sum_k M_t[r][k] * (w0[(r*17+k)*9+ij] + w1[...])
// t: 0..2 = Mh[0..2] (lora1), 3..5 = Mv[0..2] (lora2), 6 = Mid (small).
// Also zeroes the stats accumulators.
__global__ void k_weff(const float* __restrict__ w0, const float* __restrict__ w1,
                       const int* __restrict__ Mh, const int* __restrict__ Mv,
                       const int* __restrict__ Mid, float* __restrict__ ws)
{
    int idx = blockIdx.x * blockDim.x + threadIdx.x;
    if (idx < 6*REPN) ws[STATS_OFF + idx] = 0.f;
    if (idx >= REPN*63) return;
    int r   = idx / 63;
    int rem = idx % 63;
    int t   = rem / 9;
    int ij  = rem % 9;
    const int* M = (t < 3) ? (Mh + (t*REPN + r)*NKn)
                 : (t < 6) ? (Mv + ((t-3)*REPN + r)*NKn)
                           : (Mid + r*NKn);
    float acc = 0.f;
    for (int k = 0; k < NKn; ++k) {
        int m = M[k];
        if (m) acc += (float)m * (w0[(r*NKn + k)*9 + ij] + w1[(r*NKn + k)*9 + ij]);
    }
    ws[WEFF_OFF + idx] = acc;
}

// ------------------------------------------------------------- device helpers
__device__ __forceinline__ float dot9(const float n[9], const float* __restrict__ wk) {
    return n[0]*wk[0] + n[1]*wk[1] + n[2]*wk[2]
         + n[3]*wk[3] + n[4]*wk[4] + n[5]*wk[5]
         + n[6]*wk[6] + n[7]*wk[7] + n[8]*wk[8];
}

// Load the 3x3 neighborhood of padded-conv position (y,x), y,x in [0,58).
// tile row = y+i (OFFR=2 folded), tile col = x+2+j (OFFC=4 folded).
__device__ __forceinline__ void load9(const float* __restrict__ tile, int y, int x, float n[9]) {
    const float* b = tile + y*TSTR + x + 2;
    n[0] = b[0];        n[1] = b[1];        n[2] = b[2];
    n[3] = b[TSTR];     n[4] = b[TSTR+1];   n[5] = b[TSTR+2];
    n[6] = b[2*TSTR];   n[7] = b[2*TSTR+1]; n[8] = b[2*TSTR+2];
}

// lora1 = Wh0@(h+1,w+1) + Wh1@(h, w-1|57) + Wh2@(h-1|57, w)
// lora2 = Wv0@(h+1,w+1) + Wv1@(h-1|57, w) + Wv2@(h, w-1|57)
// small = Wid@(h+1,w+1)
__device__ __forceinline__ void compute3(const float* __restrict__ tile,
                                         const float* __restrict__ wk,
                                         int h, int w,
                                         float& l1, float& l2, float& sm)
{
    float n[9];
    load9(tile, h + 1, w + 1, n);              // pos0
    l1 = dot9(n, wk + 0);
    l2 = dot9(n, wk + 27);
    sm = dot9(n, wk + 54);
    int xa = (w == 0) ? 57 : (w - 1);          // posA (wrap col)
    load9(tile, h, xa, n);
    l1 += dot9(n, wk + 9);
    l2 += dot9(n, wk + 45);
    int yb = (h == 0) ? 57 : (h - 1);          // posB (wrap row)
    load9(tile, yb, w, n);
    l1 += dot9(n, wk + 18);
    l2 += dot9(n, wk + 36);
}

__device__ __forceinline__ void load_tile(const float* __restrict__ src,
                                          float* __restrict__ tile, int tid)
{
    for (int i = tid; i < TSZ; i += 256) tile[i] = 0.f;
    __syncthreads();
    const float4* s4 = (const float4*)src;
    for (int i = tid; i < HWn/4; i += 256) {
        float4 v = s4[i];
        int e = i * 4;
        int row = e / Wn;
        int col = e % Wn;                       // multiple of 4 (56%4==0)
        *(float4*)(tile + (2 + row)*TSTR + 4 + col) = v;
    }
    __syncthreads();
}

// ---------------------------------------------------------------- K1: stats
__global__ void __launch_bounds__(256) k_stats(const float* __restrict__ in,
        const int* __restrict__ rep_idx, const float* __restrict__ weff,
        float* __restrict__ stats)
{
    __shared__ __align__(16) float tile[TSZ];
    __shared__ float red[4][6];
    int bid = blockIdx.x;
    int r = bid % REPN;
    int b = bid / REPN;
    int tid = threadIdx.x;
    int cin = rep_idx[r];
    load_tile(in + ((size_t)(b*Cn + cin))*HWn, tile, tid);

    float wk[63];
    const float* wr = weff + r*63;
    #pragma unroll
    for (int i = 0; i < 63; ++i) wk[i] = wr[i];

    float s1=0.f,q1=0.f,s2=0.f,q2=0.f,s3=0.f,q3=0.f;
    for (int p = tid; p < HWn; p += 256) {
        int h = p / Wn, w = p % Wn;
        float l1, l2, sm;
        compute3(tile, wk, h, w, l1, l2, sm);
        s1 += l1; q1 += l1*l1;
        s2 += l2; q2 += l2*l2;
        s3 += sm; q3 += sm*sm;
    }
    float vals[6] = {s1,q1,s2,q2,s3,q3};
    int lane = tid & 63, wave = tid >> 6;
    #pragma unroll
    for (int q = 0; q < 6; ++q) {
        float v = vals[q];
        for (int o = 32; o; o >>= 1) v += __shfl_down(v, o, 64);
        if (lane == 0) red[wave][q] = v;
    }
    __syncthreads();
    if (tid < 6)
        atomicAdd(&stats[tid*REPN + r], red[0][tid] + red[1][tid] + red[2][tid] + red[3][tid]);
}

// ---------------------------------------------------------------- K2: output
__global__ void __launch_bounds__(256) k_out(const float* __restrict__ in,
        const int* __restrict__ rep_idx, const int* __restrict__ ghost_idx,
        const float* __restrict__ weff, const float* __restrict__ stats,
        float* __restrict__ out)
{
    __shared__ __align__(16) float tile[TSZ];
    int bid = blockIdx.x;
    int c = bid % Cn;
    int b = bid / Cn;
    int tid = threadIdx.x;

    if (c >= REPN) {                             // ghost channel copy
        int cin = ghost_idx[c - REPN];
        const float4* s4 = (const float4*)(in + ((size_t)(b*Cn + cin))*HWn);
        float4* d4 = (float4*)(out + ((size_t)(b*Cn + c))*HWn);
        for (int i = tid; i < HWn/4; i += 256) d4[i] = s4[i];
        return;
    }

    int r = c;
    int cin = rep_idx[r];
    load_tile(in + ((size_t)(b*Cn + cin))*HWn, tile, tid);

    float wk[63];
    const float* wr = weff + r*63;
    #pragma unroll
    for (int i = 0; i < 63; ++i) wk[i] = wr[i];

    const float inv = 1.0f / NSTATf;
    float m1 = stats[0*REPN+r]*inv, v1 = stats[1*REPN+r]*inv - m1*m1;
    float m2 = stats[2*REPN+r]*inv, v2 = stats[3*REPN+r]*inv - m2*m2;
    float m3 = stats[4*REPN+r]*inv, v3 = stats[5*REPN+r]*inv - m3*m3;
    float r1 = rsqrtf(v1 + EPSf), r2 = rsqrtf(v2 + EPSf), r3 = rsqrtf(v3 + EPSf);

    float* dst = out + ((size_t)(b*Cn + c))*HWn;
    for (int p = tid; p < HWn; p += 256) {
        int h = p / Wn, w = p % Wn;
        float l1, l2, sm;
        compute3(tile, wk, h, w, l1, l2, sm);
        dst[p] = (l1 - m1)*r1 + (l2 - m2)*r2 + (sm - m3)*r3 + tile[(2 + h)*TSTR + 4 + w];
    }
}

extern "C" void kernel_launch(void* const* d_in, const int* in_sizes, int n_in,
                              void* d_out, int out_size, void* d_ws, size_t ws_size,
                              hipStream_t stream) {
    const float* in   = (const float*)d_in[0];
    const float* w0   = (const float*)d_in[1];
    const float* w1   = (const float*)d_in[2];
    const int*   Mh   = (const int*)d_in[3];
    const int*   Mv   = (const int*)d_in[4];
    const int*   Mid  = (const int*)d_in[5];
    const int*   ghost= (const int*)d_in[6];
    const int*   rep  = (const int*)d_in[7];
    float* out  = (float*)d_out;
    float* ws   = (float*)d_ws;
    float* weff  = ws + WEFF_OFF;
    float* stats = ws + STATS_OFF;

    k_weff<<<(REPN*63 + 255)/256, 256, 0, stream>>>(w0, w1, Mh, Mv, Mid, ws);
    k_stats<<<Bn*REPN, 256, 0, stream>>>(in, rep, weff, stats);
    k_out<<<Bn*Cn, 256, 0, stream>>>(in, rep, ghost, weff, stats, out);
}